// Round 1
// baseline (456.247 us; speedup 1.0000x reference)
//
#include <hip/hip_runtime.h>
#include <hip/hip_bf16.h>
#include <math.h>

// Problem constants (from reference)
#define NN 8192      // num nodes
#define DD 128       // in_dim
#define KK 4096      // k = max(2, int(0.5*N))
#define NW 256       // NN/32 words per full-row bitset
#define KW 128       // KK/32 words per selected-row bitset
#define MAXNBR 768   // binomial(8192,0.01): mean 82, sd 9 -> huge margin
#define NBITBLK 8192 // bitize blocks: 8192 blk * 256 thr * 8 f4 = NN*NN/4 f4
#define NEWHBLK 512  // newh blocks fused into union grid (256 thr each)

typedef unsigned int u32;
typedef unsigned long long u64;
typedef float f32x4 __attribute__((ext_vector_type(4)));

// spread 8 bits of x to bit positions 0,4,8,...,28
__device__ __forceinline__ u32 spread4(u32 x) {
    x = (x | (x << 12)) & 0x000F000Fu;
    x = (x | (x << 6))  & 0x03030303u;
    x = (x | (x << 3))  & 0x11111111u;
    return x;
}

// ---------------------------------------------------------------------------
// K1 (fused, UNCHANGED from 437us version): blocks [0, NBITBLK): binarize g
// into row bitsets with lane-contiguous float4 loads + 4x ballot packing.
// Blocks [NBITBLK, NBITBLK+32): scores[i] = sigmoid(h[i,:]·W + b) in fp64.
// ---------------------------------------------------------------------------
__global__ void bitize_scores_kernel(const float4* __restrict__ g4,
                                     u32* __restrict__ A_bits,
                                     const float* __restrict__ h,
                                     const float* __restrict__ W,
                                     const float* __restrict__ b,
                                     float* __restrict__ scores) {
    __shared__ float w[DD];
    int tid = threadIdx.x;
    if (blockIdx.x < NBITBLK) {
        // ---- bitize ----
        int lane = tid & 63;
        long long f4base = (long long)blockIdx.x * 256 + (tid & ~63);
        const long long STRIDE = (long long)NBITBLK * 256;
        #pragma unroll
        for (int it = 0; it < 8; ++it) {
            long long fb = f4base + (long long)it * STRIDE;  // multiple of 64
            float4 v = g4[fb + lane];
            u64 m0 = __ballot(v.x != 0.0f);
            u64 m1 = __ballot(v.y != 0.0f);
            u64 m2 = __ballot(v.z != 0.0f);
            u64 m3 = __ballot(v.w != 0.0f);
            if (lane < 8) {
                u32 b0 = (u32)(m0 >> (8 * lane)) & 0xFFu;
                u32 b1 = (u32)(m1 >> (8 * lane)) & 0xFFu;
                u32 b2 = (u32)(m2 >> (8 * lane)) & 0xFFu;
                u32 b3 = (u32)(m3 >> (8 * lane)) & 0xFFu;
                u32 word = spread4(b0) | (spread4(b1) << 1) |
                           (spread4(b2) << 2) | (spread4(b3) << 3);
                A_bits[fb / 8 + lane] = word;
            }
        }
    } else {
        // ---- scores ----
        if (tid < DD) w[tid] = W[tid];
        __syncthreads();
        int i = (blockIdx.x - NBITBLK) * 256 + tid;
        const float4* hr = (const float4*)(h + i * DD);
        double x = 0.0;
        #pragma unroll
        for (int q = 0; q < DD / 4; ++q) {
            float4 v = hr[q];
            x += (double)v.x * (double)w[4 * q];
            x += (double)v.y * (double)w[4 * q + 1];
            x += (double)v.z * (double)w[4 * q + 2];
            x += (double)v.w * (double)w[4 * q + 3];
        }
        x += (double)b[0];
        double s = 1.0 / (1.0 + exp(-x));
        scores[i] = (float)s;
    }
}

// ---------------------------------------------------------------------------
// K2 (REWRITTEN): exact stable top-k via rank-sort, LDS-staged.
// 128 blocks x 512 threads; each block ranks 64 rows. All 8192 scores staged
// once per block into 32KB LDS (vs 8192 blocks each re-reading 32KB global).
// Inner loop reads are wave-uniform -> LDS broadcast, no conflicts.
// rank(i) = #{j : v_j > v_i or (v_j == v_i and j < i)}  (stable, exact)
// ---------------------------------------------------------------------------
__global__ void rank_kernel(const float* __restrict__ scores,
                            int* __restrict__ idxs,
                            float* __restrict__ vals,
                            float* __restrict__ out_idx) {
    __shared__ float sc[NN];          // 32 KB
    __shared__ int part[8][64];       // 2 KB
    int tid = threadIdx.x;            // 512 threads = 8 waves
    for (int j = tid; j < NN; j += 512) sc[j] = scores[j];
    __syncthreads();
    int l = tid & 63;                 // row within block
    int q = tid >> 6;                 // column-chunk (uniform per wave)
    int i = blockIdx.x * 64 + l;
    float vi = sc[i];
    int cnt = 0;
    int j0 = q * (NN / 8);
    #pragma unroll 8
    for (int jj = 0; jj < NN / 8; ++jj) {
        int j = j0 + jj;
        float vj = sc[j];             // same addr across wave -> broadcast
        cnt += (vj > vi || (vj == vi && j < i)) ? 1 : 0;
    }
    part[q][l] = cnt;
    __syncthreads();
    if (tid < 64) {
        int i2 = blockIdx.x * 64 + tid;
        int r = 0;
        #pragma unroll
        for (int p = 0; p < 8; ++p) r += part[p][tid];
        if (r < KK) {
            idxs[r] = i2;
            vals[r] = sc[i2];
            out_idx[r] = (float)i2;
        }
    }
}

// ---------------------------------------------------------------------------
// K3 (REWRITTEN: 256 threads, 8-way MLP): blocks [0, KK): union — 2-hop row
// of idx[r] = OR over neighbors l of A_bits[l,:] (u32/lane, 8 loads in
// flight), gather selected columns -> B_perm bits + degree -> rdeg[r].
// Blocks [KK, KK+NEWHBLK): new_h[r,:] = h[idx[r],:] * vals[r] (float4).
// ---------------------------------------------------------------------------
__global__ void union_newh_kernel(const u32* __restrict__ A_bits,
                                  const int* __restrict__ idxs,
                                  u32* __restrict__ B_perm,
                                  float* __restrict__ rdeg,
                                  const float* __restrict__ h,
                                  const float* __restrict__ vals,
                                  float* __restrict__ out_newh) {
    int tid = threadIdx.x;              // 256 threads = 4 waves
    if (blockIdx.x >= KK) {
        // ---- newh ----
        int t = (blockIdx.x - KK) * 256 + tid;   // over KK*DD/4
        int r = t >> 5;                          // 32 float4 per row
        int q = t & 31;
        float s = vals[r];
        float4 v = ((const float4*)(h + idxs[r] * DD))[q];
        ((float4*)out_newh)[t] = make_float4(v.x * s, v.y * s, v.z * s, v.w * s);
        return;
    }
    __shared__ u32 srow[NW];     // adjacency row of node idx[r]
    __shared__ u32 sOR[NW];      // OR-accumulated 2-hop row
    __shared__ int nbrs[MAXNBR];
    __shared__ int ncnt;
    __shared__ int red[256];
    int r = blockIdx.x;
    if (tid == 0) ncnt = 0;
    __syncthreads();
    int node = idxs[r];
    srow[tid] = A_bits[node * NW + tid];
    __syncthreads();
    // extract neighbor list of idx[r]
    {
        u32 word = srow[tid];
        while (word) {
            int bpos = __ffs(word) - 1;
            word &= word - 1;
            int pos = atomicAdd(&ncnt, 1);
            if (pos < MAXNBR) nbrs[pos] = tid * 32 + bpos;
        }
    }
    __syncthreads();
    int n = ncnt < MAXNBR ? ncnt : MAXNBR;
    // 8-way unrolled OR for memory-level parallelism (u32 per lane)
    u32 a0 = 0, a1 = 0, a2 = 0, a3 = 0, a4 = 0, a5 = 0, a6 = 0, a7 = 0;
    int q = 0;
    for (; q + 7 < n; q += 8) {
        a0 |= A_bits[(long long)nbrs[q]     * NW + tid];
        a1 |= A_bits[(long long)nbrs[q + 1] * NW + tid];
        a2 |= A_bits[(long long)nbrs[q + 2] * NW + tid];
        a3 |= A_bits[(long long)nbrs[q + 3] * NW + tid];
        a4 |= A_bits[(long long)nbrs[q + 4] * NW + tid];
        a5 |= A_bits[(long long)nbrs[q + 5] * NW + tid];
        a6 |= A_bits[(long long)nbrs[q + 6] * NW + tid];
        a7 |= A_bits[(long long)nbrs[q + 7] * NW + tid];
    }
    for (; q < n; ++q)
        a0 |= A_bits[(long long)nbrs[q] * NW + tid];
    sOR[tid] = ((a0 | a1) | (a2 | a3)) | ((a4 | a5) | (a6 | a7));
    __syncthreads();
    // gather selected columns: bit c of B_perm row r = sOR bit idx[c]
    int lane = tid & 63;
    int cnt = 0;
    u64* outB = (u64*)(B_perm + r * KW);
    for (int c = tid; c < KK; c += 256) {
        int id = idxs[c];               // L1-hot 16KB table, coalesced
        int bit = (sOR[id >> 5] >> (id & 31)) & 1;
        u64 m = __ballot(bit != 0);
        if (lane == 0) outB[c >> 6] = m;
        cnt += bit;
    }
    red[tid] = cnt;
    __syncthreads();
    for (int st = 128; st > 0; st >>= 1) {
        if (tid < st) red[tid] += red[tid + st];
        __syncthreads();
    }
    if (tid == 0) rdeg[r] = 1.0f / (float)red[0];   // IEEE divide matches ref
}

// ---------------------------------------------------------------------------
// K4 (REWRITTEN): one block per row; B_perm row staged in LDS; 4 float4 per
// thread; nontemporal stores (g_new is write-once, never re-read).
// g_new[r,c] = B_perm[r] bit c ? rdeg[c] : 0   (column-normalize)
// ---------------------------------------------------------------------------
__global__ void writeg_kernel(const u32* __restrict__ B_perm,
                              const float* __restrict__ rdeg,
                              float* __restrict__ g_new) {
    __shared__ u32 row[KW];
    int r = blockIdx.x;
    int tid = threadIdx.x;            // 256
    if (tid < KW) row[tid] = B_perm[r * KW + tid];
    __syncthreads();
    const float4* rd4 = (const float4*)rdeg;
    f32x4* out4 = (f32x4*)(g_new + (long long)r * KK);
    #pragma unroll
    for (int t = 0; t < 4; ++t) {
        int c4 = t * 256 + tid;
        int c = c4 * 4;
        u32 word = row[c >> 5];       // 8 lanes/word, 8 banks -> conflict-free
        float4 rv = rd4[c4];
        int sh = c & 31;              // multiple of 4, <= 28
        f32x4 o;
        o.x = ((word >> sh) & 1u) ? rv.x : 0.0f;
        o.y = ((word >> (sh + 1)) & 1u) ? rv.y : 0.0f;
        o.z = ((word >> (sh + 2)) & 1u) ? rv.z : 0.0f;
        o.w = ((word >> (sh + 3)) & 1u) ? rv.w : 0.0f;
        __builtin_nontemporal_store(o, out4 + c4);
    }
}

// ---------------------------------------------------------------------------
extern "C" void kernel_launch(void* const* d_in, const int* in_sizes, int n_in,
                              void* d_out, int out_size, void* d_ws, size_t ws_size,
                              hipStream_t stream) {
    const float* g = (const float*)d_in[0];   // [NN, NN]
    const float* h = (const float*)d_in[1];   // [NN, DD]
    const float* W = (const float*)d_in[2];   // [DD]
    const float* b = (const float*)d_in[3];   // [1]

    float* out = (float*)d_out;
    float* out_gnew = out;                          // KK*KK
    float* out_newh = out + (long long)KK * KK;     // KK*DD
    float* out_idx  = out_newh + KK * DD;           // KK

    // d_ws layout (~2.1 MB)
    char* ws = (char*)d_ws;
    float*        scores = (float*)(ws + 0);              // 32 KB
    int*          idxs   = (int*)(ws + 32768);            // 16 KB
    float*        vals   = (float*)(ws + 49152);          // 16 KB
    float*        rdeg   = (float*)(ws + 65536);          // 16 KB
    u32*          B_perm = (u32*)(ws + 98304);            // 2 MB (512B-aligned)

    // A_bits (8 MB) lives in the g_new output region; dead before writeg runs.
    u32* A_bits = (u32*)d_out;

    // K1: bitize (8192 blocks) + scores (32 blocks) fused
    bitize_scores_kernel<<<NBITBLK + NN / 256, 256, 0, stream>>>(
        (const float4*)g, A_bits, h, W, b, scores);

    // K2: stable top-k rank sort, LDS-staged (128 blocks x 512 threads)
    rank_kernel<<<NN / 64, 512, 0, stream>>>(scores, idxs, vals, out_idx);

    // K3: union (4096 blocks x 256 thr) + newh (512 blocks) fused
    union_newh_kernel<<<KK + NEWHBLK, 256, 0, stream>>>(
        A_bits, idxs, B_perm, rdeg, h, vals, out_newh);

    // K4: expand to fp32 g_new (overwrites A_bits scratch; it is dead now)
    writeg_kernel<<<KK, 256, 0, stream>>>(B_perm, rdeg, out_gnew);
}

// Round 2
// 441.989 us; speedup vs baseline: 1.0323x; 1.0323x over previous
//
#include <hip/hip_runtime.h>
#include <hip/hip_bf16.h>
#include <math.h>

// Problem constants (from reference)
#define NN 8192      // num nodes
#define DD 128       // in_dim
#define KK 4096      // k = max(2, int(0.5*N))
#define NW 256       // NN/32 words per full-row bitset
#define KW 128       // KK/32 words per selected-row bitset
#define MAXNBR 768   // binomial(8192,0.01): mean 82, sd 9 -> huge margin
#define NBITBLK 8192 // bitize blocks: 8192 blk * 256 thr * 8 f4 = NN*NN/4 f4
#define NEWHBLK 512  // newh blocks fused into union grid (256 thr each)

typedef unsigned int u32;
typedef unsigned long long u64;
typedef float f32x4 __attribute__((ext_vector_type(4)));

// spread 8 bits of x to bit positions 0,4,8,...,28
__device__ __forceinline__ u32 spread4(u32 x) {
    x = (x | (x << 12)) & 0x000F000Fu;
    x = (x | (x << 6))  & 0x03030303u;
    x = (x | (x << 3))  & 0x11111111u;
    return x;
}

// ---------------------------------------------------------------------------
// K1 (fused): blocks [0, NBITBLK): binarize g into row bitsets with
// lane-contiguous NONTEMPORAL float4 loads (g is read-once; keep L2 clean so
// A_bits stays resident for K3's 43x re-reads) + 4x ballot packing.
// Blocks [NBITBLK, NBITBLK+32): scores[i] = sigmoid(h[i,:]·W + b) in fp64.
// ---------------------------------------------------------------------------
__global__ void bitize_scores_kernel(const f32x4* __restrict__ g4,
                                     u32* __restrict__ A_bits,
                                     const float* __restrict__ h,
                                     const float* __restrict__ W,
                                     const float* __restrict__ b,
                                     float* __restrict__ scores) {
    __shared__ float w[DD];
    int tid = threadIdx.x;
    if (blockIdx.x < NBITBLK) {
        // ---- bitize ----
        int lane = tid & 63;
        long long f4base = (long long)blockIdx.x * 256 + (tid & ~63);
        const long long STRIDE = (long long)NBITBLK * 256;
        #pragma unroll
        for (int it = 0; it < 8; ++it) {
            long long fb = f4base + (long long)it * STRIDE;  // multiple of 64
            f32x4 v = __builtin_nontemporal_load(g4 + fb + lane);
            u64 m0 = __ballot(v.x != 0.0f);
            u64 m1 = __ballot(v.y != 0.0f);
            u64 m2 = __ballot(v.z != 0.0f);
            u64 m3 = __ballot(v.w != 0.0f);
            if (lane < 8) {
                u32 b0 = (u32)(m0 >> (8 * lane)) & 0xFFu;
                u32 b1 = (u32)(m1 >> (8 * lane)) & 0xFFu;
                u32 b2 = (u32)(m2 >> (8 * lane)) & 0xFFu;
                u32 b3 = (u32)(m3 >> (8 * lane)) & 0xFFu;
                u32 word = spread4(b0) | (spread4(b1) << 1) |
                           (spread4(b2) << 2) | (spread4(b3) << 3);
                A_bits[fb / 8 + lane] = word;
            }
        }
    } else {
        // ---- scores ----
        if (tid < DD) w[tid] = W[tid];
        __syncthreads();
        int i = (blockIdx.x - NBITBLK) * 256 + tid;
        const float4* hr = (const float4*)(h + i * DD);
        double x = 0.0;
        #pragma unroll
        for (int q = 0; q < DD / 4; ++q) {
            float4 v = hr[q];
            x += (double)v.x * (double)w[4 * q];
            x += (double)v.y * (double)w[4 * q + 1];
            x += (double)v.z * (double)w[4 * q + 2];
            x += (double)v.w * (double)w[4 * q + 3];
        }
        x += (double)b[0];
        double s = 1.0 / (1.0 + exp(-x));
        scores[i] = (float)s;
    }
}

// ---------------------------------------------------------------------------
// K2: exact stable top-k via rank-sort, LDS-staged.
// 128 blocks x 512 threads; each block ranks 64 rows. All 8192 scores staged
// once per block into 32KB LDS. Inner reads are wave-uniform -> broadcast.
// rank(i) = #{j : v_j > v_i or (v_j == v_i and j < i)}  (stable, exact)
// ---------------------------------------------------------------------------
__global__ void rank_kernel(const float* __restrict__ scores,
                            int* __restrict__ idxs,
                            float* __restrict__ vals,
                            float* __restrict__ out_idx) {
    __shared__ float sc[NN];          // 32 KB
    __shared__ int part[8][64];       // 2 KB
    int tid = threadIdx.x;            // 512 threads = 8 waves
    for (int j = tid; j < NN; j += 512) sc[j] = scores[j];
    __syncthreads();
    int l = tid & 63;                 // row within block
    int q = tid >> 6;                 // column-chunk (uniform per wave)
    int i = blockIdx.x * 64 + l;
    float vi = sc[i];
    int cnt = 0;
    int j0 = q * (NN / 8);
    #pragma unroll 8
    for (int jj = 0; jj < NN / 8; ++jj) {
        int j = j0 + jj;
        float vj = sc[j];             // same addr across wave -> broadcast
        cnt += (vj > vi || (vj == vi && j < i)) ? 1 : 0;
    }
    part[q][l] = cnt;
    __syncthreads();
    if (tid < 64) {
        int i2 = blockIdx.x * 64 + tid;
        int r = 0;
        #pragma unroll
        for (int p = 0; p < 8; ++p) r += part[p][tid];
        if (r < KK) {
            idxs[r] = i2;
            vals[r] = sc[i2];
            out_idx[r] = (float)i2;
        }
    }
}

// ---------------------------------------------------------------------------
// K3 (256 threads, 8-way MLP): blocks [0, KK): union — 2-hop row of idx[r]
// = OR over neighbors l of A_bits[l,:] (u32/lane, 8 loads in flight),
// gather selected columns -> B_perm bits + degree popcount -> rdeg[r].
// Blocks [KK, KK+NEWHBLK): new_h[r,:] = h[idx[r],:] * vals[r] (float4).
// ---------------------------------------------------------------------------
__global__ void union_newh_kernel(const u32* __restrict__ A_bits,
                                  const int* __restrict__ idxs,
                                  u32* __restrict__ B_perm,
                                  float* __restrict__ rdeg,
                                  const float* __restrict__ h,
                                  const float* __restrict__ vals,
                                  float* __restrict__ out_newh) {
    int tid = threadIdx.x;              // 256 threads = 4 waves
    if (blockIdx.x >= KK) {
        // ---- newh ----
        int t = (blockIdx.x - KK) * 256 + tid;   // over KK*DD/4
        int r = t >> 5;                          // 32 float4 per row
        int q = t & 31;
        float s = vals[r];
        float4 v = ((const float4*)(h + idxs[r] * DD))[q];
        ((float4*)out_newh)[t] = make_float4(v.x * s, v.y * s, v.z * s, v.w * s);
        return;
    }
    __shared__ u32 srow[NW];     // adjacency row of node idx[r]
    __shared__ u32 sOR[NW];      // OR-accumulated 2-hop row
    __shared__ int nbrs[MAXNBR];
    __shared__ int ncnt;
    __shared__ int red[256];
    int r = blockIdx.x;
    if (tid == 0) ncnt = 0;
    __syncthreads();
    int node = idxs[r];
    srow[tid] = A_bits[node * NW + tid];
    __syncthreads();
    // extract neighbor list of idx[r]
    {
        u32 word = srow[tid];
        while (word) {
            int bpos = __ffs(word) - 1;
            word &= word - 1;
            int pos = atomicAdd(&ncnt, 1);
            if (pos < MAXNBR) nbrs[pos] = tid * 32 + bpos;
        }
    }
    __syncthreads();
    int n = ncnt < MAXNBR ? ncnt : MAXNBR;
    // 8-way unrolled OR for memory-level parallelism (u32 per lane)
    u32 a0 = 0, a1 = 0, a2 = 0, a3 = 0, a4 = 0, a5 = 0, a6 = 0, a7 = 0;
    int q = 0;
    for (; q + 7 < n; q += 8) {
        a0 |= A_bits[(long long)nbrs[q]     * NW + tid];
        a1 |= A_bits[(long long)nbrs[q + 1] * NW + tid];
        a2 |= A_bits[(long long)nbrs[q + 2] * NW + tid];
        a3 |= A_bits[(long long)nbrs[q + 3] * NW + tid];
        a4 |= A_bits[(long long)nbrs[q + 4] * NW + tid];
        a5 |= A_bits[(long long)nbrs[q + 5] * NW + tid];
        a6 |= A_bits[(long long)nbrs[q + 6] * NW + tid];
        a7 |= A_bits[(long long)nbrs[q + 7] * NW + tid];
    }
    for (; q < n; ++q)
        a0 |= A_bits[(long long)nbrs[q] * NW + tid];
    sOR[tid] = ((a0 | a1) | (a2 | a3)) | ((a4 | a5) | (a6 | a7));
    __syncthreads();
    // gather selected columns: bit c of B_perm row r = sOR bit idx[c]
    int lane = tid & 63;
    int cnt = 0;
    u64* outB = (u64*)(B_perm + r * KW);
    for (int c = tid; c < KK; c += 256) {
        int id = idxs[c];               // L1-hot 16KB table, coalesced
        int bit = (sOR[id >> 5] >> (id & 31)) & 1;
        u64 m = __ballot(bit != 0);
        if (lane == 0) outB[c >> 6] = m;
        cnt += bit;
    }
    red[tid] = cnt;
    __syncthreads();
    for (int st = 128; st > 0; st >>= 1) {
        if (tid < st) red[tid] += red[tid + st];
        __syncthreads();
    }
    if (tid == 0) rdeg[r] = 1.0f / (float)red[0];   // IEEE divide matches ref
}

// ---------------------------------------------------------------------------
// K4: one block per row; B_perm row staged in LDS; 4 float4 per thread;
// nontemporal stores (g_new is write-once, never re-read).
// g_new[r,c] = B_perm[r] bit c ? rdeg[c] : 0   (column-normalize)
// ---------------------------------------------------------------------------
__global__ void writeg_kernel(const u32* __restrict__ B_perm,
                              const float* __restrict__ rdeg,
                              float* __restrict__ g_new) {
    __shared__ u32 row[KW];
    int r = blockIdx.x;
    int tid = threadIdx.x;            // 256
    if (tid < KW) row[tid] = B_perm[r * KW + tid];
    __syncthreads();
    const float4* rd4 = (const float4*)rdeg;
    f32x4* out4 = (f32x4*)(g_new + (long long)r * KK);
    #pragma unroll
    for (int t = 0; t < 4; ++t) {
        int c4 = t * 256 + tid;
        int c = c4 * 4;
        u32 word = row[c >> 5];       // 8 lanes/word, 8 banks -> conflict-free
        float4 rv = rd4[c4];
        int sh = c & 31;              // multiple of 4, <= 28
        f32x4 o;
        o.x = ((word >> sh) & 1u) ? rv.x : 0.0f;
        o.y = ((word >> (sh + 1)) & 1u) ? rv.y : 0.0f;
        o.z = ((word >> (sh + 2)) & 1u) ? rv.z : 0.0f;
        o.w = ((word >> (sh + 3)) & 1u) ? rv.w : 0.0f;
        __builtin_nontemporal_store(o, out4 + c4);
    }
}

// ---------------------------------------------------------------------------
extern "C" void kernel_launch(void* const* d_in, const int* in_sizes, int n_in,
                              void* d_out, int out_size, void* d_ws, size_t ws_size,
                              hipStream_t stream) {
    const float* g = (const float*)d_in[0];   // [NN, NN]
    const float* h = (const float*)d_in[1];   // [NN, DD]
    const float* W = (const float*)d_in[2];   // [DD]
    const float* b = (const float*)d_in[3];   // [1]

    float* out = (float*)d_out;
    float* out_gnew = out;                          // KK*KK
    float* out_newh = out + (long long)KK * KK;     // KK*DD
    float* out_idx  = out_newh + KK * DD;           // KK

    // d_ws layout (~2.1 MB)
    char* ws = (char*)d_ws;
    float*        scores = (float*)(ws + 0);              // 32 KB
    int*          idxs   = (int*)(ws + 32768);            // 16 KB
    float*        vals   = (float*)(ws + 49152);          // 16 KB
    float*        rdeg   = (float*)(ws + 65536);          // 16 KB
    u32*          B_perm = (u32*)(ws + 98304);            // 2 MB (512B-aligned)

    // A_bits (8 MB) lives in the g_new output region; dead before writeg runs.
    u32* A_bits = (u32*)d_out;

    // K1: bitize (8192 blocks, NT loads) + scores (32 blocks) fused
    bitize_scores_kernel<<<NBITBLK + NN / 256, 256, 0, stream>>>(
        (const f32x4*)g, A_bits, h, W, b, scores);

    // K2: stable top-k rank sort, LDS-staged (128 blocks x 512 threads)
    rank_kernel<<<NN / 64, 512, 0, stream>>>(scores, idxs, vals, out_idx);

    // K3: union (4096 blocks x 256 thr) + newh (512 blocks) fused
    union_newh_kernel<<<KK + NEWHBLK, 256, 0, stream>>>(
        A_bits, idxs, B_perm, rdeg, h, vals, out_newh);

    // K4: expand to fp32 g_new (overwrites A_bits scratch; it is dead now)
    writeg_kernel<<<KK, 256, 0, stream>>>(B_perm, rdeg, out_gnew);
}